// Round 1
// baseline (6166.621 us; speedup 1.0000x reference)
//
#include <hip/hip_runtime.h>

#define NN 20000      // nodes per channel
#define NE 320000     // edges per type
#define NCH 4
#define NT 16         // edge types
#define H 4
#define C 32
#define NEG 0.2f

// ---------- edge-type meta (matches reference ordering) ----------
__device__ __forceinline__ int d_dst_of(int t) {
    if (t < 4) return t;
    int i = t - 4, s = i / 3, j = i % 3;
    return j + (j >= s ? 1 : 0);
}
static inline int h_src_of(int t) { return t < 4 ? t : (t - 4) / 3; }
static inline int h_dst_of(int t) {
    if (t < 4) return t;
    int i = t - 4, s = i / 3, j = i % 3;
    return j + (j >= s ? 1 : 0);
}

// ---------- monotonic float<->uint encoding for atomicMax ----------
__device__ __forceinline__ unsigned fenc(float f) {
    unsigned u = __float_as_uint(f);
    return (u & 0x80000000u) ? ~u : (u | 0x80000000u);
}
__device__ __forceinline__ float fdec(unsigned u) {
    return (u & 0x80000000u) ? __uint_as_float(u ^ 0x80000000u) : __uint_as_float(~u);
}

// ---------- node phase: h_src = x_src @ W ; s/d attention scores ----------
// thread per (n, j) with j in [0,128); 32-lane shuffle reduce for scores
template <int FIN>
__global__ void node_phase(const float* __restrict__ xs, const float* __restrict__ xd,
                           const float* __restrict__ W,  const float* __restrict__ as_,
                           const float* __restrict__ ad_, float* __restrict__ hsrc,
                           float* __restrict__ ss, float* __restrict__ ds) {
    int tid = blockIdx.x * 256 + threadIdx.x;
    int n = tid >> 7, j = tid & 127;
    if (n >= NN) return;
    float hv = 0.f, hd = 0.f;
#pragma unroll
    for (int k = 0; k < FIN; k++) {
        float wk = W[k * 128 + j];
        hv += xs[n * FIN + k] * wk;
        hd += xd[n * FIN + k] * wk;
    }
    hsrc[n * 128 + j] = hv;
    float sv = hv * as_[j], dv = hd * ad_[j];
#pragma unroll
    for (int m = 16; m >= 1; m >>= 1) {
        sv += __shfl_xor(sv, m);
        dv += __shfl_xor(dv, m);
    }
    if ((j & 31) == 0) {
        ss[n * 4 + (j >> 5)] = sv;
        ds[n * 4 + (j >> 5)] = dv;
    }
}

// ---------- edge pass 1: logits + segment max ----------
__global__ void edge_logits(const int* __restrict__ src, const int* __restrict__ dst,
                            const float* __restrict__ ss, const float* __restrict__ ds,
                            float* __restrict__ lg, unsigned* __restrict__ emax) {
    int e = blockIdx.x * 256 + threadIdx.x;
    if (e >= NE) return;
    int s = src[e], d = dst[e];
    float4 sv = ((const float4*)ss)[s];
    float4 dv = ((const float4*)ds)[d];
    float l0 = sv.x + dv.x; l0 = l0 > 0.f ? l0 : NEG * l0;
    float l1 = sv.y + dv.y; l1 = l1 > 0.f ? l1 : NEG * l1;
    float l2 = sv.z + dv.z; l2 = l2 > 0.f ? l2 : NEG * l2;
    float l3 = sv.w + dv.w; l3 = l3 > 0.f ? l3 : NEG * l3;
    ((float4*)lg)[e] = make_float4(l0, l1, l2, l3);
    atomicMax(&emax[d * 4 + 0], fenc(l0));
    atomicMax(&emax[d * 4 + 1], fenc(l1));
    atomicMax(&emax[d * 4 + 2], fenc(l2));
    atomicMax(&emax[d * 4 + 3], fenc(l3));
}

// ---------- edge pass 2: p = exp(l - max), segment sum ----------
__global__ void edge_psum(const int* __restrict__ dst, float* __restrict__ lg,
                          const unsigned* __restrict__ emax, float* __restrict__ denom) {
    int e = blockIdx.x * 256 + threadIdx.x;
    if (e >= NE) return;
    int d = dst[e];
    float4 l = ((const float4*)lg)[e];
    uint4 m = ((const uint4*)emax)[d];
    float p0 = __expf(l.x - fdec(m.x));
    float p1 = __expf(l.y - fdec(m.y));
    float p2 = __expf(l.z - fdec(m.z));
    float p3 = __expf(l.w - fdec(m.w));
    ((float4*)lg)[e] = make_float4(p0, p1, p2, p3);
    atomicAdd(&denom[d * 4 + 0], p0);
    atomicAdd(&denom[d * 4 + 1], p1);
    atomicAdd(&denom[d * 4 + 2], p2);
    atomicAdd(&denom[d * 4 + 3], p3);
}

// ---------- edge pass 3: scatter messages, head-reduced in-register ----------
// 32 threads per edge (one per c); each sums over the 4 heads -> 1 atomic
__global__ void edge_scatter(const int* __restrict__ src, const int* __restrict__ dst,
                             const float* __restrict__ hsrc, const float* __restrict__ p,
                             const float* __restrict__ denom, float* __restrict__ acc) {
    int tid = blockIdx.x * 256 + threadIdx.x;
    int e = tid >> 5, c = tid & 31;
    if (e >= NE) return;
    int s = src[e], d = dst[e];
    float4 pv = ((const float4*)p)[e];
    float4 dn = ((const float4*)denom)[d];
    float a0 = pv.x / dn.x, a1 = pv.y / dn.y, a2 = pv.z / dn.z, a3 = pv.w / dn.w;
    const float* hb = hsrc + (size_t)s * 128;
    float val = a0 * hb[c] + a1 * hb[32 + c] + a2 * hb[64 + c] + a3 * hb[96 + c];
    atomicAdd(&acc[(size_t)d * 32 + c], val);
}

// ---------- finalize: head mean + bias-sum + channel mean + relu ----------
__global__ void finalize(const float* __restrict__ acc, const float* __restrict__ b,
                         float* __restrict__ out, int concat) {
    int idx = blockIdx.x * 256 + threadIdx.x;  // over 4*NN*32
    if (idx >= NCH * NN * 32) return;
    int c = idx & 31;
    int n = (idx >> 5) % NN;
    int ch = idx / (NN * 32);
    float bsum = 0.f;
#pragma unroll
    for (int t = 0; t < NT; t++)
        if (d_dst_of(t) == ch) bsum += b[t * 32 + c];
    float v = (acc[idx] * 0.25f + bsum) * 0.25f;  // /H then /num_incoming_types
    v = v > 0.f ? v : 0.f;
    if (concat) out[(size_t)n * 128 + ch * 32 + c] = v;
    else        out[(size_t)ch * NN * 32 + (size_t)n * 32 + c] = v;
}

extern "C" void kernel_launch(void* const* d_in, const int* in_sizes, int n_in,
                              void* d_out, int out_size, void* d_ws, size_t ws_size,
                              hipStream_t stream) {
    const float* x   = (const float*)d_in[0];   // [4, NN, 1]
    const int*   edg = (const int*)d_in[1];     // [16, 2, NE]
    const float* W1  = (const float*)d_in[2];   // [16, 1, 128]
    const float* as1 = (const float*)d_in[3];   // [16, 4, 32]
    const float* ad1 = (const float*)d_in[4];
    const float* b1  = (const float*)d_in[5];   // [16, 32]
    const float* W2  = (const float*)d_in[6];   // [16, 32, 128]
    const float* as2 = (const float*)d_in[7];
    const float* ad2 = (const float*)d_in[8];
    const float* b2  = (const float*)d_in[9];
    float* out = (float*)d_out;

    char* w = (char*)d_ws;
    float*    hsrc  = (float*)w;    w += (size_t)NN * 128 * 4;
    float*    ss    = (float*)w;    w += (size_t)NN * 4 * 4;
    float*    ds    = (float*)w;    w += (size_t)NN * 4 * 4;
    unsigned* emax  = (unsigned*)w; w += (size_t)NN * 4 * 4;
    float*    denom = (float*)w;    w += (size_t)NN * 4 * 4;
    float*    p     = (float*)w;    w += (size_t)NE * 4 * 4;
    float*    acc   = (float*)w;    w += (size_t)NCH * NN * 32 * 4;
    float*    x1    = (float*)w;    w += (size_t)NCH * NN * 32 * 4;

    const int nodeBlocks = (NN * 128 + 255) / 256;
    const int edgeBlocks = (NE + 255) / 256;
    const int scatBlocks = (NE * 32 + 255) / 256;
    const int finBlocks  = (NCH * NN * 32 + 255) / 256;

    for (int layer = 0; layer < 2; layer++) {
        hipMemsetAsync(acc, 0, (size_t)NCH * NN * 32 * 4, stream);
        for (int t = 0; t < NT; t++) {
            int sc = h_src_of(t), dc = h_dst_of(t);
            const int* srcp = edg + (size_t)t * 2 * NE;
            const int* dstp = srcp + NE;
            if (layer == 0) {
                node_phase<1><<<nodeBlocks, 256, 0, stream>>>(
                    x + (size_t)sc * NN, x + (size_t)dc * NN,
                    W1 + (size_t)t * 128, as1 + (size_t)t * 128, ad1 + (size_t)t * 128,
                    hsrc, ss, ds);
            } else {
                node_phase<32><<<nodeBlocks, 256, 0, stream>>>(
                    x1 + (size_t)sc * NN * 32, x1 + (size_t)dc * NN * 32,
                    W2 + (size_t)t * 32 * 128, as2 + (size_t)t * 128, ad2 + (size_t)t * 128,
                    hsrc, ss, ds);
            }
            hipMemsetAsync(emax,  0, (size_t)NN * 4 * 4, stream);
            hipMemsetAsync(denom, 0, (size_t)NN * 4 * 4, stream);
            edge_logits<<<edgeBlocks, 256, 0, stream>>>(srcp, dstp, ss, ds, p, emax);
            edge_psum<<<edgeBlocks, 256, 0, stream>>>(dstp, p, emax, denom);
            edge_scatter<<<scatBlocks, 256, 0, stream>>>(srcp, dstp, hsrc, p, denom,
                                                         acc + (size_t)dc * NN * 32);
        }
        if (layer == 0)
            finalize<<<finBlocks, 256, 0, stream>>>(acc, b1, x1, 0);
        else
            finalize<<<finBlocks, 256, 0, stream>>>(acc, b2, out, 1);
    }
}

// Round 2
// 1755.127 us; speedup vs baseline: 3.5135x; 3.5135x over previous
//
#include <hip/hip_runtime.h>
#include <math.h>

#define NN 20000
#define NE 320000
#define NT 16
#define NEG 0.2f
#define PR 8          // placement bin-range partitions (20000/8 = 2500 bins, 10KB LDS)

__device__ __forceinline__ int d_src_of(int t) { return t < 4 ? t : (t - 4) / 3; }
__device__ __forceinline__ int d_dst_of(int t) {
    if (t < 4) return t;
    int i = t - 4, s = i / 3, j = i % 3;
    return j + (j >= s ? 1 : 0);
}
static inline int h_src_of(int t) { return t < 4 ? t : (t - 4) / 3; }
static inline int h_dst_of(int t) {
    if (t < 4) return t;
    int i = t - 4, s = i / 3, j = i % 3;
    return j + (j >= s ? 1 : 0);
}

// ============ CSR build: histogram (LDS, coalesced flush) ============
// grid 16 types * 8 edge-chunks * 2 bin-ranges = 256 WGs
__global__ void hist_kernel(const int* __restrict__ edges, int* __restrict__ counts) {
    int wg = blockIdx.x;
    int r = wg & 1, chunk = (wg >> 1) & 7, t = wg >> 4;
    __shared__ int h[10000];
    for (int i = threadIdx.x; i < 10000; i += 256) h[i] = 0;
    __syncthreads();
    const int* dstp = edges + (size_t)t * 2 * NE + NE;
    int e0 = chunk * 40000, e1 = e0 + 40000;
    int rb = r * 10000;
    for (int e = e0 + threadIdx.x; e < e1; e += 256) {
        unsigned d = (unsigned)(dstp[e] - rb);
        if (d < 10000u) atomicAdd(&h[d], 1);
    }
    __syncthreads();
    for (int i = threadIdx.x; i < 10000; i += 256) {
        int v = h[i];
        if (v) atomicAdd(&counts[t * NN + rb + i], v);  // coalesced contiguous atomics
    }
}

// ============ CSR build: exclusive scan per type -> row_ptr ============
__global__ void scan_kernel(const int* __restrict__ counts, int* __restrict__ row_ptr) {
    int t = blockIdx.x, tid = threadIdx.x;
    __shared__ int buf[256];
    int running = 0;
    for (int base = 0; base < NN; base += 256) {
        int i = base + tid;
        int v = (i < NN) ? counts[t * NN + i] : 0;
        buf[tid] = v;
        __syncthreads();
        for (int off = 1; off < 256; off <<= 1) {
            int x = (tid >= off) ? buf[tid - off] : 0;
            __syncthreads();
            buf[tid] += x;
            __syncthreads();
        }
        int excl = buf[tid] - v;
        if (i < NN) row_ptr[t * (NN + 1) + i] = running + excl;
        int tot = buf[255];
        __syncthreads();
        running += tot;
    }
    if (tid == 0) row_ptr[t * (NN + 1) + NN] = running;
}

// ============ CSR build: placement with LDS cursors (no global atomics) ============
// grid 16 types * PR ranges; each WG owns 2500 bins, scans all NE edges of its type
__global__ void place_kernel(const int* __restrict__ edges, const int* __restrict__ row_ptr,
                             int* __restrict__ csr_src) {
    int wg = blockIdx.x;
    int t = wg / PR, r = wg % PR;
    int base = r * 2500;
    __shared__ int cur[2500];
    for (int i = threadIdx.x; i < 2500; i += 256) cur[i] = row_ptr[t * (NN + 1) + base + i];
    __syncthreads();
    const int* srcp = edges + (size_t)t * 2 * NE;
    const int* dstp = srcp + NE;
    for (int e = threadIdx.x; e < NE; e += 256) {
        unsigned d = (unsigned)(dstp[e] - base);
        if (d < 2500u) {
            int pos = atomicAdd(&cur[d], 1);  // LDS atomic
            csr_src[(size_t)t * NE + pos] = srcp[e];
        }
    }
}

// ============ precompute u = reduce(W * a) over c ============
// u1s/u1d: [16][4]; u2s/u2d: [16][32][4]
__global__ void precompute_u(const float* __restrict__ W1, const float* __restrict__ as1,
                             const float* __restrict__ ad1, const float* __restrict__ W2,
                             const float* __restrict__ as2, const float* __restrict__ ad2,
                             float* __restrict__ u1s, float* __restrict__ u1d,
                             float* __restrict__ u2s, float* __restrict__ u2d) {
    int t = blockIdx.x, tid = threadIdx.x;  // 128 threads
    int k = tid >> 2, h = tid & 3;
    float ss = 0.f, dd = 0.f;
    for (int c = 0; c < 32; c++) {
        float w = W2[(size_t)t * 4096 + k * 128 + h * 32 + c];
        ss += w * as2[t * 128 + h * 32 + c];
        dd += w * ad2[t * 128 + h * 32 + c];
    }
    u2s[(t * 32 + k) * 4 + h] = ss;
    u2d[(t * 32 + k) * 4 + h] = dd;
    if (tid < 4) {
        int hh = tid;
        float s1 = 0.f, d1 = 0.f;
        for (int c = 0; c < 32; c++) {
            float w = W1[t * 128 + hh * 32 + c];
            s1 += w * as1[t * 128 + hh * 32 + c];
            d1 += w * ad1[t * 128 + hh * 32 + c];
        }
        u1s[t * 4 + hh] = s1;
        u1d[t * 4 + hh] = d1;
    }
}

// ============ Layer 1: fused online-softmax attention + aggregation ============
// Fin=1 => h_src[s,h,c] = x_s * W1[h,c]; aggregate g1[t][d][h] = sum_e alpha_eh * x_s
__global__ void layer1_fused(const float* __restrict__ x, const int* __restrict__ csr_src,
                             const int* __restrict__ row_ptr, const float* __restrict__ u1s,
                             const float* __restrict__ u1d, float4* __restrict__ g1) {
    int t = blockIdx.y;
    int d = blockIdx.x * 256 + threadIdx.x;
    if (d >= NN) return;
    int sc = d_src_of(t), dc = d_dst_of(t);
    float xd = x[dc * NN + d];
    float4 usv = ((const float4*)u1s)[t];
    float4 udv = ((const float4*)u1d)[t];
    float us[4] = {usv.x, usv.y, usv.z, usv.w};
    float dl[4] = {xd * udv.x, xd * udv.y, xd * udv.z, xd * udv.w};
    int rb = row_ptr[t * (NN + 1) + d], re = row_ptr[t * (NN + 1) + d + 1];
    float m[4], dn[4] = {0, 0, 0, 0}, a[4] = {0, 0, 0, 0};
    m[0] = m[1] = m[2] = m[3] = -INFINITY;
    for (int i = rb; i < re; i++) {
        int s = csr_src[(size_t)t * NE + i];
        float xs = x[sc * NN + s];
#pragma unroll
        for (int h = 0; h < 4; h++) {
            float l = xs * us[h] + dl[h];
            l = l > 0.f ? l : NEG * l;
            if (l > m[h]) {
                float rr = __expf(m[h] - l);
                a[h] *= rr; dn[h] *= rr; m[h] = l;
            }
            float p = __expf(l - m[h]);
            dn[h] += p;
            a[h] += p * xs;
        }
    }
    float4 g;
    g.x = (re > rb) ? a[0] / dn[0] : 0.f;
    g.y = (re > rb) ? a[1] / dn[1] : 0.f;
    g.z = (re > rb) ? a[2] / dn[2] : 0.f;
    g.w = (re > rb) ? a[3] / dn[3] : 0.f;
    g1[t * NN + d] = g;
}

// ============ Layer 1 transform: x1 = relu( (sum_t (g1.W1)/H + b_t) / 4 ) ============
__global__ void transform1(const float4* __restrict__ g1, const float* __restrict__ W1,
                           const float* __restrict__ b1, float* __restrict__ x1) {
    int idx = blockIdx.x * 256 + threadIdx.x;  // [ch][n][c]
    if (idx >= 4 * NN * 32) return;
    int c = idx & 31;
    int n = (idx >> 5) % NN;
    int ch = idx / (NN * 32);
    float sum = 0.f, bs = 0.f;
#pragma unroll
    for (int t = 0; t < NT; t++) {
        if (d_dst_of(t) == ch) {
            float4 g = g1[t * NN + n];
            const float* w = W1 + t * 128 + c;
            sum += 0.25f * (g.x * w[0] + g.y * w[32] + g.z * w[64] + g.w * w[96]);
            bs += b1[t * 32 + c];
        }
    }
    float v = 0.25f * (sum + bs);
    x1[idx] = v > 0.f ? v : 0.f;
}

// ============ Layer 2 scores: ss/ds[t][n][h] = x1_row . u2 ============
__global__ void scores2(const float* __restrict__ x1, const float* __restrict__ u2s,
                        const float* __restrict__ u2d, float4* __restrict__ ss,
                        float4* __restrict__ ds) {
    int t = blockIdx.y;
    int n = blockIdx.x * 256 + threadIdx.x;
    if (n >= NN) return;
    int sc = d_src_of(t), dc = d_dst_of(t);
    const float* xsr = x1 + ((size_t)sc * NN + n) * 32;
    const float* xdr = x1 + ((size_t)dc * NN + n) * 32;
    float s4[4] = {0, 0, 0, 0}, d4[4] = {0, 0, 0, 0};
    for (int k = 0; k < 32; k++) {
        float xs = xsr[k], xd = xdr[k];
        float4 uk = ((const float4*)u2s)[t * 32 + k];
        float4 vk = ((const float4*)u2d)[t * 32 + k];
        s4[0] += xs * uk.x; s4[1] += xs * uk.y; s4[2] += xs * uk.z; s4[3] += xs * uk.w;
        d4[0] += xd * vk.x; d4[1] += xd * vk.y; d4[2] += xd * vk.z; d4[3] += xd * vk.w;
    }
    ss[t * NN + n] = make_float4(s4[0], s4[1], s4[2], s4[3]);
    ds[t * NN + n] = make_float4(d4[0], d4[1], d4[2], d4[3]);
}

// ============ Layer 2: fused online softmax + x1-row aggregation + W2 transform ============
// 32 lanes per dst (lane = k). g[d,h,k] = sum_e alpha_eh * x1[s,k]; then o_c = g.W2/H
__global__ __launch_bounds__(256) void layer2_scatter(
    const float* __restrict__ x1, const int* __restrict__ csr_src,
    const int* __restrict__ row_ptr, const float4* __restrict__ ss,
    const float4* __restrict__ ds, const float* __restrict__ W2, float* __restrict__ acc,
    int t, int sc, int dc, int init) {
    __shared__ float W2s[32 * 128];
    __shared__ float gl[8 * 128];
    for (int i = threadIdx.x; i < 4096; i += 256) W2s[i] = W2[(size_t)t * 4096 + i];
    __syncthreads();
    int group = threadIdx.x >> 5, lane = threadIdx.x & 31;
    int d = blockIdx.x * 8 + group;  // grid = NN/8 = 2500, exact
    float4 dsv = ds[t * NN + d];
    float dl[4] = {dsv.x, dsv.y, dsv.z, dsv.w};
    int rb = row_ptr[t * (NN + 1) + d], re = row_ptr[t * (NN + 1) + d + 1];
    float m[4], dn[4] = {0, 0, 0, 0}, val[4] = {0, 0, 0, 0};
    m[0] = m[1] = m[2] = m[3] = -INFINITY;
    for (int i = rb; i < re; i++) {
        int s = csr_src[(size_t)t * NE + i];
        float4 ssv = ss[t * NN + s];
        float sl[4] = {ssv.x, ssv.y, ssv.z, ssv.w};
        float xk = x1[((size_t)sc * NN + s) * 32 + lane];  // coalesced 128B / group
#pragma unroll
        for (int h = 0; h < 4; h++) {
            float l = sl[h] + dl[h];
            l = l > 0.f ? l : NEG * l;
            if (l > m[h]) {
                float rr = __expf(m[h] - l);
                val[h] *= rr; dn[h] *= rr; m[h] = l;
            }
            float p = __expf(l - m[h]);
            dn[h] += p;
            val[h] += p * xk;
        }
    }
#pragma unroll
    for (int h = 0; h < 4; h++) {
        float g = (re > rb) ? val[h] / dn[h] : 0.f;
        gl[group * 128 + h * 32 + lane] = g;
    }
    __syncthreads();
    float o = 0.f;
    for (int k = 0; k < 32; k++) {
#pragma unroll
        for (int h = 0; h < 4; h++)
            o += gl[group * 128 + h * 32 + k] * W2s[k * 128 + h * 32 + lane];
    }
    o *= 0.25f;  // head mean
    size_t oi = ((size_t)dc * NN + d) * 32 + lane;
    if (init) acc[oi] = o;
    else      acc[oi] += o;
}

// ============ finalize: out = relu( (acc + sum_t b_t) / 4 ), concat layout ============
__global__ void finalize2(const float* __restrict__ acc, const float* __restrict__ b2,
                          float* __restrict__ out) {
    int idx = blockIdx.x * 256 + threadIdx.x;
    if (idx >= 4 * NN * 32) return;
    int c = idx & 31;
    int n = (idx >> 5) % NN;
    int ch = idx / (NN * 32);
    float bs = 0.f;
#pragma unroll
    for (int t = 0; t < NT; t++)
        if (d_dst_of(t) == ch) bs += b2[t * 32 + c];
    float v = 0.25f * (acc[idx] + bs);
    out[(size_t)n * 128 + ch * 32 + c] = v > 0.f ? v : 0.f;
}

extern "C" void kernel_launch(void* const* d_in, const int* in_sizes, int n_in,
                              void* d_out, int out_size, void* d_ws, size_t ws_size,
                              hipStream_t stream) {
    const float* x   = (const float*)d_in[0];
    const int*   edg = (const int*)d_in[1];
    const float* W1  = (const float*)d_in[2];
    const float* as1 = (const float*)d_in[3];
    const float* ad1 = (const float*)d_in[4];
    const float* b1  = (const float*)d_in[5];
    const float* W2  = (const float*)d_in[6];
    const float* as2 = (const float*)d_in[7];
    const float* ad2 = (const float*)d_in[8];
    const float* b2  = (const float*)d_in[9];
    float* out = (float*)d_out;

    char* w = (char*)d_ws;
    auto carve = [&](size_t bytes) {
        void* p = (void*)w;
        w += (bytes + 255) & ~(size_t)255;
        return p;
    };
    int*   csr_src = (int*)carve((size_t)NT * NE * 4);        // 20.5 MB
    int*   row_ptr = (int*)carve((size_t)NT * (NN + 1) * 4);  // 1.3 MB
    int*   counts  = (int*)carve((size_t)NT * NN * 4);        // 1.3 MB
    float* u1s     = (float*)carve(NT * 4 * 4);
    float* u1d     = (float*)carve(NT * 4 * 4);
    float* u2s     = (float*)carve(NT * 32 * 4 * 4);
    float* u2d     = (float*)carve(NT * 32 * 4 * 4);
    float* g1      = (float*)carve((size_t)NT * NN * 4 * 4);  // 5.1 MB
    float* ss      = (float*)carve((size_t)NT * NN * 4 * 4);  // 5.1 MB
    float* ds      = (float*)carve((size_t)NT * NN * 4 * 4);  // 5.1 MB
    float* x1      = (float*)carve((size_t)4 * NN * 32 * 4);  // 10.2 MB
    float* acc     = (float*)carve((size_t)4 * NN * 32 * 4);  // 10.2 MB

    // ---- CSR build (shared by both layers) ----
    hipMemsetAsync(counts, 0, (size_t)NT * NN * 4, stream);
    hist_kernel<<<NT * 8 * 2, 256, 0, stream>>>(edg, counts);
    scan_kernel<<<NT, 256, 0, stream>>>(counts, row_ptr);
    place_kernel<<<NT * PR, 256, 0, stream>>>(edg, row_ptr, csr_src);
    precompute_u<<<NT, 128, 0, stream>>>(W1, as1, ad1, W2, as2, ad2, u1s, u1d, u2s, u2d);

    // ---- Layer 1 ----
    dim3 gtn((NN + 255) / 256, NT);
    layer1_fused<<<gtn, 256, 0, stream>>>(x, csr_src, row_ptr, u1s, u1d, (float4*)g1);
    transform1<<<(4 * NN * 32 + 255) / 256, 256, 0, stream>>>((const float4*)g1, W1, b1, x1);

    // ---- Layer 2 ----
    scores2<<<gtn, 256, 0, stream>>>(x1, u2s, u2d, (float4*)ss, (float4*)ds);
    for (int t = 0; t < NT; t++) {
        layer2_scatter<<<NN / 8, 256, 0, stream>>>(x1, csr_src, row_ptr, (const float4*)ss,
                                                   (const float4*)ds, W2, acc, t,
                                                   h_src_of(t), h_dst_of(t), t < 4 ? 1 : 0);
    }
    finalize2<<<(4 * NN * 32 + 255) / 256, 256, 0, stream>>>(acc, b2, out);
}

// Round 3
// 901.413 us; speedup vs baseline: 6.8411x; 1.9471x over previous
//
#include <hip/hip_runtime.h>
#include <math.h>

#define NN 20000
#define NE 320000
#define NT 16
#define NEG 0.2f
#define NCHUNK 16
#define CHSZ (NE / NCHUNK)   // 20000

__device__ __forceinline__ int d_src_of(int t) { return t < 4 ? t : (t - 4) / 3; }
__device__ __forceinline__ int d_dst_of(int t) {
    if (t < 4) return t;
    int i = t - 4, s = i / 3, j = i % 3;
    return j + (j >= s ? 1 : 0);
}
static inline int h_dst_of(int t) {
    if (t < 4) return t;
    int i = t - 4, s = i / 3, j = i % 3;
    return j + (j >= s ? 1 : 0);
}

// ============ CSR build 1: per-(type,chunk) histogram, 16-bit packed LDS ============
__global__ void hist2(const int* __restrict__ edges, int* __restrict__ counts) {
    int t = blockIdx.x >> 4, chunk = blockIdx.x & 15;
    __shared__ unsigned h[NN / 2];  // 40 KB, 2 bins per word
    for (int i = threadIdx.x; i < NN / 2; i += 256) h[i] = 0;
    __syncthreads();
    const int* dstp = edges + (size_t)t * 2 * NE + NE + chunk * CHSZ;
    for (int e = threadIdx.x; e < CHSZ; e += 256) {
        int d = dstp[e];
        atomicAdd(&h[d >> 1], (d & 1) ? 0x10000u : 1u);
    }
    __syncthreads();
    int* cout = counts + ((size_t)t * NCHUNK + chunk) * NN;
    for (int i = threadIdx.x; i < NN / 2; i += 256) {
        unsigned v = h[i];
        cout[2 * i]     = (int)(v & 0xffffu);
        cout[2 * i + 1] = (int)(v >> 16);
    }
}

// ============ CSR build 2: totals + in-place exclusive prefix over chunks ============
__global__ void sumtot(int* __restrict__ counts, int* __restrict__ totals) {
    int idx = blockIdx.x * 256 + threadIdx.x;  // t*NN + bin
    if (idx >= NT * NN) return;
    int t = idx / NN, bin = idx % NN;
    int* base = counts + (size_t)t * NCHUNK * NN + bin;
    int run = 0;
#pragma unroll
    for (int c = 0; c < NCHUNK; c++) {
        int v = base[c * NN];
        base[c * NN] = run;
        run += v;
    }
    totals[idx] = run;
}

// ============ CSR build 3: exclusive scan of totals per type -> row_ptr ============
__global__ void scan_kernel(const int* __restrict__ totals, int* __restrict__ row_ptr) {
    int t = blockIdx.x, tid = threadIdx.x;
    __shared__ int buf[256];
    int running = 0;
    for (int base = 0; base < NN; base += 256) {
        int i = base + tid;
        int v = (i < NN) ? totals[t * NN + i] : 0;
        buf[tid] = v;
        __syncthreads();
        for (int off = 1; off < 256; off <<= 1) {
            int x = (tid >= off) ? buf[tid - off] : 0;
            __syncthreads();
            buf[tid] += x;
            __syncthreads();
        }
        int excl = buf[tid] - v;
        if (i < NN) row_ptr[t * (NN + 1) + i] = running + excl;
        int tot = buf[255];
        __syncthreads();
        running += tot;
    }
    if (tid == 0) row_ptr[t * (NN + 1) + NN] = running;
}

// ============ CSR build 4: chunkbase = prefix + row_ptr ============
__global__ void addbase(int* __restrict__ counts, const int* __restrict__ row_ptr) {
    int idx = blockIdx.x * 256 + threadIdx.x;
    if (idx >= NT * NCHUNK * NN) return;
    int bin = idx % NN;
    int t = idx / (NCHUNK * NN);
    counts[idx] += row_ptr[t * (NN + 1) + bin];
}

// ============ CSR build 5: placement, 16-bit packed LDS cursors ============
__global__ void place2(const int* __restrict__ edges, const int* __restrict__ chunkbase,
                       int* __restrict__ csr_src) {
    int t = blockIdx.x >> 4, chunk = blockIdx.x & 15;
    __shared__ unsigned cur[NN / 2];
    for (int i = threadIdx.x; i < NN / 2; i += 256) cur[i] = 0;
    __syncthreads();
    const int* srcp = edges + (size_t)t * 2 * NE + chunk * CHSZ;
    const int* dstp = srcp + NE;
    const int* cb = chunkbase + ((size_t)t * NCHUNK + chunk) * NN;
    int* cs = csr_src + (size_t)t * NE;
    for (int e = threadIdx.x; e < CHSZ; e += 256) {
        int d = dstp[e];
        unsigned old = atomicAdd(&cur[d >> 1], (d & 1) ? 0x10000u : 1u);
        int off = (d & 1) ? (int)(old >> 16) : (int)(old & 0xffffu);
        cs[cb[d] + off] = srcp[e];
    }
}

// ============ precompute u = reduce(W * a) over c ============
__global__ void precompute_u(const float* __restrict__ W1, const float* __restrict__ as1,
                             const float* __restrict__ ad1, const float* __restrict__ W2,
                             const float* __restrict__ as2, const float* __restrict__ ad2,
                             float* __restrict__ u1s, float* __restrict__ u1d,
                             float* __restrict__ u2s, float* __restrict__ u2d) {
    int t = blockIdx.x, tid = threadIdx.x;  // 128 threads
    int k = tid >> 2, h = tid & 3;
    float ss = 0.f, dd = 0.f;
    for (int c = 0; c < 32; c++) {
        float w = W2[(size_t)t * 4096 + k * 128 + h * 32 + c];
        ss += w * as2[t * 128 + h * 32 + c];
        dd += w * ad2[t * 128 + h * 32 + c];
    }
    u2s[(t * 32 + k) * 4 + h] = ss;
    u2d[(t * 32 + k) * 4 + h] = dd;
    if (tid < 4) {
        int hh = tid;
        float s1 = 0.f, d1 = 0.f;
        for (int c = 0; c < 32; c++) {
            float w = W1[t * 128 + hh * 32 + c];
            s1 += w * as1[t * 128 + hh * 32 + c];
            d1 += w * ad1[t * 128 + hh * 32 + c];
        }
        u1s[t * 4 + hh] = s1;
        u1d[t * 4 + hh] = d1;
    }
}

// ============ Layer 1: fused online-softmax attention + aggregation ============
__global__ void layer1_fused(const float* __restrict__ x, const int* __restrict__ csr_src,
                             const int* __restrict__ row_ptr, const float* __restrict__ u1s,
                             const float* __restrict__ u1d, float4* __restrict__ g1) {
    int t = blockIdx.y;
    int d = blockIdx.x * 256 + threadIdx.x;
    if (d >= NN) return;
    int sc = d_src_of(t), dc = d_dst_of(t);
    float xd = x[dc * NN + d];
    float4 usv = ((const float4*)u1s)[t];
    float4 udv = ((const float4*)u1d)[t];
    float us[4] = {usv.x, usv.y, usv.z, usv.w};
    float dl[4] = {xd * udv.x, xd * udv.y, xd * udv.z, xd * udv.w};
    int rb = row_ptr[t * (NN + 1) + d], re = row_ptr[t * (NN + 1) + d + 1];
    float m[4], dn[4] = {0, 0, 0, 0}, a[4] = {0, 0, 0, 0};
    m[0] = m[1] = m[2] = m[3] = -INFINITY;
    for (int i = rb; i < re; i++) {
        int s = csr_src[(size_t)t * NE + i];
        float xs = x[sc * NN + s];
#pragma unroll
        for (int h = 0; h < 4; h++) {
            float l = xs * us[h] + dl[h];
            l = l > 0.f ? l : NEG * l;
            if (l > m[h]) {
                float rr = __expf(m[h] - l);
                a[h] *= rr; dn[h] *= rr; m[h] = l;
            }
            float p = __expf(l - m[h]);
            dn[h] += p;
            a[h] += p * xs;
        }
    }
    float4 g;
    g.x = (re > rb) ? a[0] / dn[0] : 0.f;
    g.y = (re > rb) ? a[1] / dn[1] : 0.f;
    g.z = (re > rb) ? a[2] / dn[2] : 0.f;
    g.w = (re > rb) ? a[3] / dn[3] : 0.f;
    g1[t * NN + d] = g;
}

// ============ Layer 1 transform ============
__global__ void transform1(const float4* __restrict__ g1, const float* __restrict__ W1,
                           const float* __restrict__ b1, float* __restrict__ x1) {
    int idx = blockIdx.x * 256 + threadIdx.x;  // [ch][n][c]
    if (idx >= 4 * NN * 32) return;
    int c = idx & 31;
    int n = (idx >> 5) % NN;
    int ch = idx / (NN * 32);
    float sum = 0.f, bs = 0.f;
#pragma unroll
    for (int t = 0; t < NT; t++) {
        if (d_dst_of(t) == ch) {
            float4 g = g1[t * NN + n];
            const float* w = W1 + t * 128 + c;
            sum += 0.25f * (g.x * w[0] + g.y * w[32] + g.z * w[64] + g.w * w[96]);
            bs += b1[t * 32 + c];
        }
    }
    float v = 0.25f * (sum + bs);
    x1[idx] = v > 0.f ? v : 0.f;
}

// ============ Layer 2 scores ============
__global__ void scores2(const float* __restrict__ x1, const float* __restrict__ u2s,
                        const float* __restrict__ u2d, float4* __restrict__ ss,
                        float4* __restrict__ ds) {
    int t = blockIdx.y;
    int n = blockIdx.x * 256 + threadIdx.x;
    if (n >= NN) return;
    int sc = d_src_of(t), dc = d_dst_of(t);
    const float* xsr = x1 + ((size_t)sc * NN + n) * 32;
    const float* xdr = x1 + ((size_t)dc * NN + n) * 32;
    float s4[4] = {0, 0, 0, 0}, d4[4] = {0, 0, 0, 0};
    for (int k = 0; k < 32; k++) {
        float xs = xsr[k], xd = xdr[k];
        float4 uk = ((const float4*)u2s)[t * 32 + k];
        float4 vk = ((const float4*)u2d)[t * 32 + k];
        s4[0] += xs * uk.x; s4[1] += xs * uk.y; s4[2] += xs * uk.z; s4[3] += xs * uk.w;
        d4[0] += xd * vk.x; d4[1] += xd * vk.y; d4[2] += xd * vk.z; d4[3] += xd * vk.w;
    }
    ss[t * NN + n] = make_float4(s4[0], s4[1], s4[2], s4[3]);
    ds[t * NN + n] = make_float4(d4[0], d4[1], d4[2], d4[3]);
}

// ============ Layer 2: fused softmax + aggregation + W2 transform ============
// blockIdx.y = dst channel; `types` holds one type per channel (race-free wave)
__global__ __launch_bounds__(256) void layer2_scatter(
    const float* __restrict__ x1, const int* __restrict__ csr_src,
    const int* __restrict__ row_ptr, const float4* __restrict__ ss,
    const float4* __restrict__ ds, const float* __restrict__ W2, float* __restrict__ acc,
    int4 types, int init) {
    int dc = blockIdx.y;
    int t = (dc == 0) ? types.x : (dc == 1) ? types.y : (dc == 2) ? types.z : types.w;
    int sc = d_src_of(t);
    __shared__ float W2s[32 * 128];
    __shared__ float gl[8 * 128];
    for (int i = threadIdx.x; i < 4096; i += 256) W2s[i] = W2[(size_t)t * 4096 + i];
    __syncthreads();
    int group = threadIdx.x >> 5, lane = threadIdx.x & 31;
    int d = blockIdx.x * 8 + group;  // grid.x = NN/8 = 2500, exact
    float4 dsv = ds[t * NN + d];
    float dl[4] = {dsv.x, dsv.y, dsv.z, dsv.w};
    int rb = row_ptr[t * (NN + 1) + d], re = row_ptr[t * (NN + 1) + d + 1];
    float m[4], dn[4] = {0, 0, 0, 0}, val[4] = {0, 0, 0, 0};
    m[0] = m[1] = m[2] = m[3] = -INFINITY;
    for (int i = rb; i < re; i++) {
        int s = csr_src[(size_t)t * NE + i];
        float4 ssv = ss[t * NN + s];
        float sl[4] = {ssv.x, ssv.y, ssv.z, ssv.w};
        float xk = x1[((size_t)sc * NN + s) * 32 + lane];
#pragma unroll
        for (int h = 0; h < 4; h++) {
            float l = sl[h] + dl[h];
            l = l > 0.f ? l : NEG * l;
            if (l > m[h]) {
                float rr = __expf(m[h] - l);
                val[h] *= rr; dn[h] *= rr; m[h] = l;
            }
            float p = __expf(l - m[h]);
            dn[h] += p;
            val[h] += p * xk;
        }
    }
#pragma unroll
    for (int h = 0; h < 4; h++) {
        float g = (re > rb) ? val[h] / dn[h] : 0.f;
        gl[group * 128 + h * 32 + lane] = g;
    }
    __syncthreads();
    float o = 0.f;
    for (int k = 0; k < 32; k++) {
#pragma unroll
        for (int h = 0; h < 4; h++)
            o += gl[group * 128 + h * 32 + k] * W2s[k * 128 + h * 32 + lane];
    }
    o *= 0.25f;  // head mean
    size_t oi = ((size_t)dc * NN + d) * 32 + lane;
    if (init) acc[oi] = o;
    else      acc[oi] += o;
}

// ============ finalize ============
__global__ void finalize2(const float* __restrict__ acc, const float* __restrict__ b2,
                          float* __restrict__ out) {
    int idx = blockIdx.x * 256 + threadIdx.x;
    if (idx >= 4 * NN * 32) return;
    int c = idx & 31;
    int n = (idx >> 5) % NN;
    int ch = idx / (NN * 32);
    float bs = 0.f;
#pragma unroll
    for (int t = 0; t < NT; t++)
        if (d_dst_of(t) == ch) bs += b2[t * 32 + c];
    float v = 0.25f * (acc[idx] + bs);
    out[(size_t)n * 128 + ch * 32 + c] = v > 0.f ? v : 0.f;
}

extern "C" void kernel_launch(void* const* d_in, const int* in_sizes, int n_in,
                              void* d_out, int out_size, void* d_ws, size_t ws_size,
                              hipStream_t stream) {
    const float* x   = (const float*)d_in[0];
    const int*   edg = (const int*)d_in[1];
    const float* W1  = (const float*)d_in[2];
    const float* as1 = (const float*)d_in[3];
    const float* ad1 = (const float*)d_in[4];
    const float* b1  = (const float*)d_in[5];
    const float* W2  = (const float*)d_in[6];
    const float* as2 = (const float*)d_in[7];
    const float* ad2 = (const float*)d_in[8];
    const float* b2  = (const float*)d_in[9];
    float* out = (float*)d_out;

    char* w = (char*)d_ws;
    auto carve = [&](size_t bytes) {
        void* p = (void*)w;
        w += (bytes + 255) & ~(size_t)255;
        return p;
    };
    int*   csr_src = (int*)carve((size_t)NT * NE * 4);            // 20.5 MB
    int*   row_ptr = (int*)carve((size_t)NT * (NN + 1) * 4);      // 1.3 MB
    float* u1s     = (float*)carve(NT * 4 * 4);
    float* u1d     = (float*)carve(NT * 4 * 4);
    float* u2s     = (float*)carve(NT * 32 * 4 * 4);
    float* u2d     = (float*)carve(NT * 32 * 4 * 4);
    float* g1      = (float*)carve((size_t)NT * NN * 4 * 4);      // 5.1 MB
    float* x1      = (float*)carve((size_t)4 * NN * 32 * 4);      // 10.2 MB
    // union region: {counts 20.5MB + totals 1.3MB} then {ss,ds,acc = 20.5MB}
    char*  ub      = (char*)carve((size_t)NT * NCHUNK * NN * 4 + (size_t)NT * NN * 4 + 512);
    int*   counts  = (int*)ub;
    int*   totals  = (int*)(ub + (size_t)NT * NCHUNK * NN * 4);
    float* ss      = (float*)ub;
    float* ds      = ss + (size_t)NT * NN * 4;
    float* acc     = ds + (size_t)NT * NN * 4;

    // ---- CSR build (single-pass chunked, no global atomics) ----
    hist2<<<NT * NCHUNK, 256, 0, stream>>>(edg, counts);
    sumtot<<<(NT * NN + 255) / 256, 256, 0, stream>>>(counts, totals);
    scan_kernel<<<NT, 256, 0, stream>>>(totals, row_ptr);
    addbase<<<(NT * NCHUNK * NN + 255) / 256, 256, 0, stream>>>(counts, row_ptr);
    place2<<<NT * NCHUNK, 256, 0, stream>>>(edg, counts, csr_src);
    precompute_u<<<NT, 128, 0, stream>>>(W1, as1, ad1, W2, as2, ad2, u1s, u1d, u2s, u2d);

    // ---- Layer 1 ----
    dim3 gtn((NN + 255) / 256, NT);
    layer1_fused<<<gtn, 256, 0, stream>>>(x, csr_src, row_ptr, u1s, u1d, (float4*)g1);
    transform1<<<(4 * NN * 32 + 255) / 256, 256, 0, stream>>>((const float4*)g1, W1, b1, x1);

    // ---- Layer 2 ----
    scores2<<<gtn, 256, 0, stream>>>(x1, u2s, u2d, (float4*)ss, (float4*)ds);
    int lists[4][4]; int cnt[4] = {0, 0, 0, 0};
    for (int t = 0; t < NT; t++) { int dc = h_dst_of(t); lists[dc][cnt[dc]++] = t; }
    for (int j = 0; j < 4; j++) {
        int4 ty = make_int4(lists[0][j], lists[1][j], lists[2][j], lists[3][j]);
        layer2_scatter<<<dim3(NN / 8, 4), 256, 0, stream>>>(
            x1, csr_src, row_ptr, (const float4*)ss, (const float4*)ds, W2, acc, ty, j == 0);
    }
    finalize2<<<(4 * NN * 32 + 255) / 256, 256, 0, stream>>>(acc, b2, out);
}